// Round 15
// baseline (282.404 us; speedup 1.0000x reference)
//
#include <hip/hip_runtime.h>
#include <hip/hip_bf16.h>
#include <math.h>

// Problem constants
#define B_   64
#define T_   64
#define E_   512
#define DM   1024   // d_model
#define DI   2048   // d_inner
#define DS   16     // d_state
#define DTR  64     // dt_rank
#define M_   4096   // B*T rows

typedef __hip_bfloat16 bf16;
typedef __attribute__((ext_vector_type(8))) short bf16x8;   // 8 bf16 = 4 VGPRs
typedef __attribute__((ext_vector_type(4))) float f32x4;

__device__ __forceinline__ float b2f(unsigned short s) {
    return __uint_as_float(((unsigned)s) << 16);
}

// ---------------------------------------------------------------------------
// bf16 MFMA GEMM (generic): C[M x N] = act(A @ B + bias)
// Best-measured core (R3..R14): BK=32, 256 threads, 2x2 wave grid, both
// operands staged via global_load_lds width=16 into linear [row][32] LDS.
// Full-K (no split) with fused bias+relu+bf16 epilogue — R15 replaces the
// split-K partial round-trips for the tail GEMMs (BN=64 gives enough blocks).
// ACT: 0 none, 1 relu.  OUTBF: bf16 out when 1, fp32 otherwise.
// ---------------------------------------------------------------------------
template<int BM, int BN, int ACT, int OUTBF>
__global__ __launch_bounds__(256) void gemm_mfma(
    const bf16* __restrict__ A, int lda,
    const bf16* __restrict__ Bt, int ldb,
    void* __restrict__ Cv, int ldc,
    const float* __restrict__ bias,
    int Ndim, int Kdim)
{
    __shared__ __align__(16) bf16 As[BM * 32];
    __shared__ __align__(16) bf16 Bs[BN * 32];
    const int tid  = threadIdx.x;
    const int wave = tid >> 6;
    const int lane = tid & 63;
    const int bm = blockIdx.y * BM;
    const int bn = blockIdx.x * BN;
    const int lrow = lane >> 2;               // 0..15
    const int lkc  = (lane & 3) * 8;          // k element offset 0,8,16,24
    constexpr int RPW = (BM + BN) / 4;        // rows staged per wave
    constexpr int NI  = RPW / 16;             // issues per wave
    constexpr int WMT = BM / 32;
    constexpr int WNT = BN / 32;
    const int wm = (wave >> 1) * (BM / 2);
    const int wn = (wave & 1) * (BN / 2);
    const int fm = lane & 15;
    const int fq = lane >> 4;

    f32x4 acc[WMT][WNT];
    #pragma unroll
    for (int i = 0; i < WMT; ++i)
        #pragma unroll
        for (int j = 0; j < WNT; ++j)
            acc[i][j] = (f32x4){0.f, 0.f, 0.f, 0.f};

    for (int k0 = 0; k0 < Kdim; k0 += 32) {
        #pragma unroll
        for (int i = 0; i < NI; ++i) {
            int rowbase = wave * RPW + i * 16;   // wave-uniform
            int row = rowbase + lrow;
            if (rowbase < BM) {
                const bf16* ga = A + (size_t)(bm + row) * lda + k0 + lkc;
                __builtin_amdgcn_global_load_lds(
                    (const __attribute__((address_space(1))) void*)ga,
                    (__attribute__((address_space(3))) void*)&As[rowbase * 32],
                    16, 0, 0);
            } else {
                int brow = bn + row - BM;
                if (brow >= Ndim) brow = Ndim - 1;
                const bf16* gb = Bt + (size_t)brow * ldb + k0 + lkc;
                __builtin_amdgcn_global_load_lds(
                    (const __attribute__((address_space(1))) void*)gb,
                    (__attribute__((address_space(3))) void*)&Bs[(rowbase - BM) * 32],
                    16, 0, 0);
            }
        }
        __syncthreads();
        bf16x8 a[WMT], b[WNT];
        #pragma unroll
        for (int i = 0; i < WMT; ++i)
            a[i] = *(const bf16x8*)&As[(wm + i * 16 + fm) * 32 + fq * 8];
        #pragma unroll
        for (int j = 0; j < WNT; ++j)
            b[j] = *(const bf16x8*)&Bs[(wn + j * 16 + fm) * 32 + fq * 8];
        #pragma unroll
        for (int i = 0; i < WMT; ++i)
            #pragma unroll
            for (int j = 0; j < WNT; ++j)
                acc[i][j] = __builtin_amdgcn_mfma_f32_16x16x32_bf16(
                    a[i], b[j], acc[i][j], 0, 0, 0);
        __syncthreads();
    }

    #pragma unroll
    for (int i = 0; i < WMT; ++i) {
        int rowb = bm + wm + i * 16 + fq * 4;
        #pragma unroll
        for (int j = 0; j < WNT; ++j) {
            int col = bn + wn + j * 16 + fm;
            if (col < Ndim) {
                float bv = bias ? bias[col] : 0.f;
                #pragma unroll
                for (int r = 0; r < 4; ++r) {
                    float v = acc[i][j][r] + bv;
                    if (ACT == 1) v = fmaxf(v, 0.f);
                    size_t off = (size_t)(rowb + r) * ldc + col;
                    if (OUTBF) ((bf16*)Cv)[off] = __float2bfloat16(v);
                    else       ((float*)Cv)[off] = v;
                }
            }
        }
    }
}

// ---------------------------------------------------------------------------
// G1 specialized + Wc fold merged (R11) + G2 fused (R14). Grid (36, 32):
//   blockIdx.x <  32: xz = xb @ W_in tile; conv+silu fused epilogue (R8);
//     then (xi blocks) the G2 partial  proj[bm.., 0:96) += tile @ WxTᵀ
//     via per-wave MFMA on the LDS-resident conv output, atomicAdd to proj.
//   blockIdx.x >= 32: WcT = W1T @ Wob^T (the W_out@W1 weight fold).
// ---------------------------------------------------------------------------
__global__ __launch_bounds__(256) void gemm_g1_conv(
    const bf16* __restrict__ A,      // xb (M_,1024)
    const bf16* __restrict__ Bt,     // WinT (4096,1024)
    bf16* __restrict__ xcb,          // (M_,2048) silu(conv(xi))
    bf16* __restrict__ zb,           // (M_,2048) z
    const float* __restrict__ conv_w,
    const float* __restrict__ conv_b,
    const bf16* __restrict__ W1T,    // (512,1024)
    const bf16* __restrict__ Wob,    // (2048,1024)
    bf16* __restrict__ WcT,          // (512,2048) out
    const bf16* __restrict__ WxT,    // (96,2048)
    float* __restrict__ proj)        // (M_,96) fp32, pre-zeroed; += G2 partials
{
    constexpr int XS = 136;                       // padded X stride (elems)
    __shared__ __align__(16) bf16 smem[128 * XS]; // 34816 B
    const int tid  = threadIdx.x;
    const int wave = tid >> 6;
    const int lane = tid & 63;
    const int lrow = lane >> 2;
    const int lkc  = (lane & 3) * 8;
    const int wm = (wave >> 1) * 64;
    const int fm = lane & 15;
    const int fq = lane >> 4;

    if (blockIdx.x >= 32) {
        // ---------------- fold path: BM=128, BN=64 ----------------
        const int fbm = (blockIdx.x - 32) * 128;   // over M=512
        const int fbn = blockIdx.y * 64;           // over N=2048
        const int fwn = (wave & 1) * 32;
        f32x4 facc[4][2];
        #pragma unroll
        for (int i = 0; i < 4; ++i)
            #pragma unroll
            for (int j = 0; j < 2; ++j)
                facc[i][j] = (f32x4){0.f, 0.f, 0.f, 0.f};

        for (int k0 = 0; k0 < 1024; k0 += 32) {
            #pragma unroll
            for (int i = 0; i < 3; ++i) {          // 48 rows per wave
                int rowbase = wave * 48 + i * 16;  // wave-uniform
                int row = rowbase + lrow;
                if (rowbase < 128) {
                    const bf16* ga = W1T + (size_t)(fbm + row) * 1024 + k0 + lkc;
                    __builtin_amdgcn_global_load_lds(
                        (const __attribute__((address_space(1))) void*)ga,
                        (__attribute__((address_space(3))) void*)&smem[rowbase * 32],
                        16, 0, 0);
                } else {
                    const bf16* gb = Wob + (size_t)(fbn + row - 128) * 1024 + k0 + lkc;
                    __builtin_amdgcn_global_load_lds(
                        (const __attribute__((address_space(1))) void*)gb,
                        (__attribute__((address_space(3))) void*)&smem[4096 + (rowbase - 128) * 32],
                        16, 0, 0);
                }
            }
            __syncthreads();
            bf16x8 a[4], b[2];
            #pragma unroll
            for (int i = 0; i < 4; ++i)
                a[i] = *(const bf16x8*)&smem[(wm + i * 16 + fm) * 32 + fq * 8];
            #pragma unroll
            for (int j = 0; j < 2; ++j)
                b[j] = *(const bf16x8*)&smem[4096 + (fwn + j * 16 + fm) * 32 + fq * 8];
            #pragma unroll
            for (int i = 0; i < 4; ++i)
                #pragma unroll
                for (int j = 0; j < 2; ++j)
                    facc[i][j] = __builtin_amdgcn_mfma_f32_16x16x32_bf16(
                        a[i], b[j], facc[i][j], 0, 0, 0);
            __syncthreads();
        }
        #pragma unroll
        for (int i = 0; i < 4; ++i) {
            int rowb = fbm + wm + i * 16 + fq * 4;
            #pragma unroll
            for (int j = 0; j < 2; ++j) {
                int col = fbn + fwn + j * 16 + fm;
                #pragma unroll
                for (int r = 0; r < 4; ++r)
                    WcT[(size_t)(rowb + r) * 2048 + col] =
                        __float2bfloat16(facc[i][j][r]);
            }
        }
        return;
    }

    // ---------------- G1 path (unchanged R8 core) ----------------
    const int bm = blockIdx.y * 128;
    const int bn = blockIdx.x * 128;
    const int wn = (wave & 1) * 64;

    f32x4 acc[4][4];
    #pragma unroll
    for (int i = 0; i < 4; ++i)
        #pragma unroll
        for (int j = 0; j < 4; ++j)
            acc[i][j] = (f32x4){0.f, 0.f, 0.f, 0.f};

    for (int k0 = 0; k0 < 1024; k0 += 32) {
        #pragma unroll
        for (int i = 0; i < 4; ++i) {
            int rowbase = wave * 64 + i * 16;     // wave-uniform
            int row = rowbase + lrow;
            if (rowbase < 128) {
                const bf16* ga = A + (size_t)(bm + row) * 1024 + k0 + lkc;
                __builtin_amdgcn_global_load_lds(
                    (const __attribute__((address_space(1))) void*)ga,
                    (__attribute__((address_space(3))) void*)&smem[rowbase * 32],
                    16, 0, 0);
            } else {
                const bf16* gb = Bt + (size_t)(bn + row - 128) * 1024 + k0 + lkc;
                __builtin_amdgcn_global_load_lds(
                    (const __attribute__((address_space(1))) void*)gb,
                    (__attribute__((address_space(3))) void*)&smem[4096 + (rowbase - 128) * 32],
                    16, 0, 0);
            }
        }
        __syncthreads();
        bf16x8 a[4], b[4];
        #pragma unroll
        for (int i = 0; i < 4; ++i)
            a[i] = *(const bf16x8*)&smem[(wm + i * 16 + fm) * 32 + fq * 8];
        #pragma unroll
        for (int j = 0; j < 4; ++j)
            b[j] = *(const bf16x8*)&smem[4096 + (wn + j * 16 + fm) * 32 + fq * 8];
        #pragma unroll
        for (int i = 0; i < 4; ++i)
            #pragma unroll
            for (int j = 0; j < 4; ++j)
                acc[i][j] = __builtin_amdgcn_mfma_f32_16x16x32_bf16(
                    a[i], b[j], acc[i][j], 0, 0, 0);
        __syncthreads();   // As/Bs region dead -> reusable as conv buffer
    }

    if (bn < 2048) {
        #pragma unroll
        for (int i = 0; i < 4; ++i) {
            int rowb = wm + i * 16 + fq * 4;
            #pragma unroll
            for (int j = 0; j < 4; ++j) {
                int col = wn + j * 16 + fm;
                #pragma unroll
                for (int r = 0; r < 4; ++r)
                    smem[(rowb + r) * XS + col] = __float2bfloat16(acc[i][j][r]);
            }
        }
        __syncthreads();
        {
            int col = tid & 127;
            int seq = tid >> 7;                   // 0 or 1
            int gcol = bn + col;
            float4 cw = *(const float4*)&conv_w[gcol * 4];
            float cb = conv_b[gcol];
            float w0 = 0.f, w1 = 0.f, w2 = 0.f;
            int base = seq * 64;
            for (int t = 0; t < 64; ++t) {
                int idx = (base + t) * XS + col;
                float cur = __bfloat162float(smem[idx]);
                float cacc = cb;
                cacc = fmaf(w0, cw.x, cacc); cacc = fmaf(w1, cw.y, cacc);
                cacc = fmaf(w2, cw.z, cacc); cacc = fmaf(cur, cw.w, cacc);
                smem[idx] = __float2bfloat16(__fdividef(cacc, 1.f + __expf(-cacc)));
                w0 = w1; w1 = w2; w2 = cur;
            }
        }
        __syncthreads();
        // coalesced bf16x8 store -> xcb
        #pragma unroll
        for (int it = 0; it < 8; ++it) {
            int g = it * 256 + tid;               // 2048 groups of 8
            int row = g >> 4;
            int cg = (g & 15) * 8;
            bf16x8 v = *(const bf16x8*)&smem[row * XS + cg];
            *(bf16x8*)&xcb[(size_t)(bm + row) * 2048 + bn + cg] = v;
        }
        // ---- fused G2 partial: proj[bm+m, n] += sum_k tile[m,k]*WxT[n,bn+k]
        {
            const int mw = wave * 32;
            f32x4 dacc[2][6];
            #pragma unroll
            for (int i = 0; i < 2; ++i)
                #pragma unroll
                for (int j = 0; j < 6; ++j)
                    dacc[i][j] = (f32x4){0.f, 0.f, 0.f, 0.f};
            #pragma unroll
            for (int kit = 0; kit < 4; ++kit) {
                bf16x8 bfrag[6], afrag[2];
                #pragma unroll
                for (int j = 0; j < 6; ++j)
                    bfrag[j] = *(const bf16x8*)(WxT
                        + (size_t)(j * 16 + fm) * 2048 + bn + kit * 32 + fq * 8);
                #pragma unroll
                for (int i = 0; i < 2; ++i)
                    afrag[i] = *(const bf16x8*)&smem[
                        (mw + i * 16 + fm) * XS + kit * 32 + fq * 8];
                #pragma unroll
                for (int i = 0; i < 2; ++i)
                    #pragma unroll
                    for (int j = 0; j < 6; ++j)
                        dacc[i][j] = __builtin_amdgcn_mfma_f32_16x16x32_bf16(
                            afrag[i], bfrag[j], dacc[i][j], 0, 0, 0);
            }
            #pragma unroll
            for (int i = 0; i < 2; ++i) {
                int rowb = bm + mw + i * 16 + fq * 4;
                #pragma unroll
                for (int j = 0; j < 6; ++j) {
                    int n = j * 16 + fm;
                    #pragma unroll
                    for (int r = 0; r < 4; ++r)
                        atomicAdd(&proj[(size_t)(rowb + r) * 96 + n],
                                  dacc[i][j][r]);
                }
            }
        }
    } else {
        #pragma unroll
        for (int i = 0; i < 4; ++i) {
            int rowb = bm + wm + i * 16 + fq * 4;
            #pragma unroll
            for (int j = 0; j < 4; ++j) {
                int col = bn - 2048 + wn + j * 16 + fm;
                #pragma unroll
                for (int r = 0; r < 4; ++r)
                    zb[(size_t)(rowb + r) * 2048 + col] =
                        __float2bfloat16(acc[i][j][r]);
            }
        }
    }
}

// ---------------------------------------------------------------------------
// Fused G3 + selective scan (R13). Grid (8, 64).
// ---------------------------------------------------------------------------
__global__ __launch_bounds__(256) void scan_g3_kernel(
    const float* __restrict__ proj,   // (M_,96): [0:64) dt_raw, [64:80) B, [80:96) C
    const bf16*  __restrict__ WdT,    // (2048, 64)
    const float* __restrict__ b_dt,   // (2048)
    bf16* __restrict__ xcy,           // (M_, DI) in: xc, out: gated y
    const bf16*  __restrict__ zb,     // (M_, DI) z
    const float* __restrict__ A_log,  // (DI, 16)
    const float* __restrict__ D_skip) // (DI)
{
    __shared__ float BC[64][32];                  // 8 KB
    __shared__ __align__(16) bf16 Adt[64 * 64];   // 8 KB (dt_raw bf16)
    __shared__ __align__(16) bf16 Bdt[256 * 64];  // 32 KB WdT slice; later dt_s
    const int tid  = threadIdx.x;
    const int wave = tid >> 6;
    const int lane = tid & 63;
    const int b  = blockIdx.y;        // 0..63
    const int dg = blockIdx.x;        // d in [dg*256, dg*256+256)
    const int fm = lane & 15;
    const int fq = lane >> 4;

    // BC staging
    for (int i = tid; i < 64 * 32; i += 256) {
        int t = i >> 5, c = i & 31;
        BC[t][c] = proj[(size_t)(b * 64 + t) * 96 + 64 + c];
    }
    // A staging: dt_raw (64 rows x 64 k) fp32 -> bf16
    {
        int arow = tid >> 2;              // 0..63
        int ak = (tid & 3) * 16;          // 0,16,32,48
        const float* ga = proj + (size_t)(b * 64 + arow) * 96 + ak;
        float4 v0 = *(const float4*)(ga + 0);
        float4 v1 = *(const float4*)(ga + 4);
        float4 v2 = *(const float4*)(ga + 8);
        float4 v3 = *(const float4*)(ga + 12);
        bf16 o[16] = {
            __float2bfloat16(v0.x), __float2bfloat16(v0.y),
            __float2bfloat16(v0.z), __float2bfloat16(v0.w),
            __float2bfloat16(v1.x), __float2bfloat16(v1.y),
            __float2bfloat16(v1.z), __float2bfloat16(v1.w),
            __float2bfloat16(v2.x), __float2bfloat16(v2.y),
            __float2bfloat16(v2.z), __float2bfloat16(v2.w),
            __float2bfloat16(v3.x), __float2bfloat16(v3.y),
            __float2bfloat16(v3.z), __float2bfloat16(v3.w)};
        *(bf16x8*)&Adt[arow * 64 + ak]     = *(const bf16x8*)&o[0];
        *(bf16x8*)&Adt[arow * 64 + ak + 8] = *(const bf16x8*)&o[8];
    }
    // B staging: WdT rows [dg*256, +256). Row = 64 bf16 = 128 B -> 8 lanes
    // of 16 B per row -> 8 rows per issue -> 8 issues per wave (64 rows).
    #pragma unroll
    for (int i = 0; i < 8; ++i) {
        int rowbase = wave * 64 + i * 8;      // wave-uniform
        const bf16* gb = WdT + (size_t)(dg * 256 + rowbase + (lane >> 3)) * 64
                             + (lane & 7) * 8;
        __builtin_amdgcn_global_load_lds(
            (const __attribute__((address_space(1))) void*)gb,
            (__attribute__((address_space(3))) void*)&Bdt[rowbase * 64],
            16, 0, 0);
    }
    __syncthreads();

    // MFMA: M=64(t), N=256(d), K=64. Wave w covers d-range [w*64, w*64+64).
    f32x4 acc[4][4];
    #pragma unroll
    for (int i = 0; i < 4; ++i)
        #pragma unroll
        for (int j = 0; j < 4; ++j)
            acc[i][j] = (f32x4){0.f, 0.f, 0.f, 0.f};
    #pragma unroll
    for (int k0 = 0; k0 < 64; k0 += 32) {
        bf16x8 a[4], bfr[4];
        #pragma unroll
        for (int i = 0; i < 4; ++i)
            a[i] = *(const bf16x8*)&Adt[(i * 16 + fm) * 64 + k0 + fq * 8];
        #pragma unroll
        for (int j = 0; j < 4; ++j)
            bfr[j] = *(const bf16x8*)&Bdt[(wave * 64 + j * 16 + fm) * 64 + k0 + fq * 8];
        #pragma unroll
        for (int i = 0; i < 4; ++i)
            #pragma unroll
            for (int j = 0; j < 4; ++j)
                acc[i][j] = __builtin_amdgcn_mfma_f32_16x16x32_bf16(
                    a[i], bfr[j], acc[i][j], 0, 0, 0);
    }
    __syncthreads();                      // all Bdt reads done
    bf16* dt_s = Bdt;                     // alias: dt_s[t*256 + dlocal]
    #pragma unroll
    for (int j = 0; j < 4; ++j) {
        int dloc = wave * 64 + j * 16 + fm;
        float bv = b_dt[dg * 256 + dloc];
        #pragma unroll
        for (int i = 0; i < 4; ++i) {
            #pragma unroll
            for (int r = 0; r < 4; ++r) {
                int t = i * 16 + fq * 4 + r;
                float v = acc[i][j][r] + bv;
                v = (v > 20.f) ? v : __logf(1.f + __expf(v));   // softplus
                dt_s[t * 256 + dloc] = __float2bfloat16(v);
            }
        }
    }
    __syncthreads();

    // ---- scan main loop (R9 semantics; dt from LDS) ----
    const int d = dg * 256 + tid;
    float av[16];
    const float4* alp = (const float4*)(A_log + d * 16);
    *(float4*)&av[0]  = alp[0];
    *(float4*)&av[4]  = alp[1];
    *(float4*)&av[8]  = alp[2];
    *(float4*)&av[12] = alp[3];
    float A[16];
    #pragma unroll
    for (int n = 0; n < 16; ++n) A[n] = -__expf(av[n]);
    const float Dv = D_skip[d];
    float h[16];
    #pragma unroll
    for (int n = 0; n < 16; ++n) h[n] = 0.f;

    #pragma unroll 2
    for (int t = 0; t < T_; ++t) {
        int row = b * T_ + t;
        size_t off = (size_t)row * DI + d;
        float xv = __bfloat162float(xcy[off]);
        float dt = __bfloat162float(dt_s[t * 256 + tid]);
        float dtx = dt * xv;
        float y = 0.f;
        #pragma unroll
        for (int n = 0; n < 16; ++n) {
            float dA = __expf(dt * A[n]);
            h[n] = fmaf(dA, h[n], dtx * BC[t][n]);
            y = fmaf(h[n], BC[t][16 + n], y);
        }
        float sk = fmaf(xv, Dv, y);
        float z = __bfloat162float(zb[off]);
        float g = __fdividef(z, 1.f + __expf(-z));          // silu(z)
        xcy[off] = __float2bfloat16(sk * g);
    }
}

// ---------------------------------------------------------------------------
// prep: concat->bf16 + zero proj (blocks [0,4096)), W_out bf16 convert
// ([4096,6144)), transposes of W_x/W_dt/W1/W2 ([6144,7104)) and W_in
// ([7104,11200)).
// ---------------------------------------------------------------------------
__global__ __launch_bounds__(256) void prep_kernel(
    const float* __restrict__ sp, const float* __restrict__ tp,
    bf16* __restrict__ xb, float* __restrict__ proj,
    const float* __restrict__ W_in,  bf16* __restrict__ WinT,
    const float* __restrict__ W_out, bf16* __restrict__ Wob,
    const float* __restrict__ W_x,   bf16* __restrict__ WxT,
    const float* __restrict__ W_dt,  bf16* __restrict__ WdT,
    const float* __restrict__ W1,    bf16* __restrict__ W1T,
    const float* __restrict__ W2,    bf16* __restrict__ W2T)
{
    __shared__ float tile[32][33];
    const int b = blockIdx.x;
    const int tid = threadIdx.x;
    if (b < 4096) {
        int idx = b * 256 + tid;
        int row = idx >> 8;
        int c4 = (idx & 255) * 4;
        const float* src = (c4 < 512) ? (sp + (size_t)row * 512 + c4)
                                      : (tp + (size_t)row * 512 + (c4 - 512));
        float4 v = *(const float4*)src;
        bf16* dst = xb + (size_t)row * 1024 + c4;
        dst[0] = __float2bfloat16(v.x); dst[1] = __float2bfloat16(v.y);
        dst[2] = __float2bfloat16(v.z); dst[3] = __float2bfloat16(v.w);
        if (idx < 98304)   // zero proj (393216 floats) for fused-G2 atomicAdd
            *(float4*)(proj + (size_t)idx * 4) = make_float4(0.f, 0.f, 0.f, 0.f);
        return;
    }
    if (b < 6144) {
        int idx = (b - 4096) * 1024 + tid * 4;
        float4 v = *(const float4*)(W_out + idx);
        bf16 o[4] = {__float2bfloat16(v.x), __float2bfloat16(v.y),
                     __float2bfloat16(v.z), __float2bfloat16(v.w)};
        *(short4*)&Wob[idx] = *(short4*)o;
        return;
    }
    const float* W; bf16* Wt; int K, N, tb;
    if      (b < 6336) { W = W_x;  Wt = WxT;  K = 2048; N = 96;   tb = b - 6144; }
    else if (b < 6464) { W = W_dt; Wt = WdT;  K = 64;   N = 2048; tb = b - 6336; }
    else if (b < 6976) { W = W1;   Wt = W1T;  K = 1024; N = 512;  tb = b - 6464; }
    else if (b < 7104) { W = W2;   Wt = W2T;  K = 512;  N = 256;  tb = b - 6976; }
    else               { W = W_in; Wt = WinT; K = 1024; N = 4096; tb = b - 7104; }
    int nb = N / 32;
    int bn = (tb % nb) * 32, bk = (tb / nb) * 32;
    int tx = tid & 31, ty = tid >> 5;
    #pragma unroll
    for (int i = 0; i < 32; i += 8)
        tile[ty + i][tx] = W[(size_t)(bk + ty + i) * N + bn + tx];
    __syncthreads();
    #pragma unroll
    for (int i = 0; i < 32; i += 8)
        Wt[(size_t)(bn + ty + i) * K + bk + tx] = __float2bfloat16(tile[tx][ty + i]);
}

// ---------------------------------------------------------------------------
// Head: out[row, 0:6] = h2[row, :] @ W3 + b3.  One wave per row. h2 is bf16.
// ---------------------------------------------------------------------------
__global__ __launch_bounds__(256) void head_kernel(
    const bf16* __restrict__ h2, const float* __restrict__ W3,
    const float* __restrict__ b3, float* __restrict__ out)
{
    int row = blockIdx.x * 4 + (threadIdx.x >> 6);
    int lane = threadIdx.x & 63;
    const bf16* hr = h2 + (size_t)row * 256;
    float acc[6] = {0.f, 0.f, 0.f, 0.f, 0.f, 0.f};
    #pragma unroll
    for (int kk = 0; kk < 4; ++kk) {
        int c = lane + kk * 64;
        float s = __bfloat162float(hr[c]);
        #pragma unroll
        for (int n = 0; n < 6; ++n) acc[n] = fmaf(s, W3[c * 6 + n], acc[n]);
    }
    #pragma unroll
    for (int n = 0; n < 6; ++n) {
        float v = acc[n];
        #pragma unroll
        for (int off = 32; off > 0; off >>= 1) v += __shfl_down(v, off);
        if (lane == 0) out[(size_t)row * 6 + n] = v + b3[n];
    }
}

// ---------------------------------------------------------------------------
extern "C" void kernel_launch(void* const* d_in, const int* in_sizes, int n_in,
                              void* d_out, int out_size, void* d_ws, size_t ws_size,
                              hipStream_t stream)
{
    const float* spatial  = (const float*)d_in[0];
    const float* temporal = (const float*)d_in[1];
    const float* W_in     = (const float*)d_in[2];
    const float* conv_w   = (const float*)d_in[3];
    const float* conv_b   = (const float*)d_in[4];
    const float* W_x      = (const float*)d_in[5];
    const float* W_dt     = (const float*)d_in[6];
    const float* b_dt     = (const float*)d_in[7];
    const float* A_log    = (const float*)d_in[8];
    const float* D_skip   = (const float*)d_in[9];
    const float* W_out    = (const float*)d_in[10];
    const float* W1       = (const float*)d_in[11];
    const float* b1       = (const float*)d_in[12];
    const float* W2       = (const float*)d_in[13];
    const float* b2       = (const float*)d_in[14];
    const float* W3       = (const float*)d_in[15];
    const float* b3       = (const float*)d_in[16];
    float* out = (float*)d_out;

    // Workspace layout (bytes), total 93,716,480.
    char* w = (char*)d_ws;
    bf16*  xcb  = (bf16*)(w);                 // (M_,2048) xc -> y (in-place)
    bf16*  zb   = (bf16*)(w + 16777216);      // (M_,2048) 16 MiB
    bf16*  h1   = (bf16*)(w + 33554432);      // (M_,512) bf16 4 MiB
    bf16*  h2   = (bf16*)(w + 37748736);      // (M_,256) bf16 2 MiB
    bf16*  xb   = (bf16*)(w + 67108864);      // (M_,1024) 8 MiB
    bf16*  WinT = (bf16*)(w + 75497472);      // (4096,1024) 8 MiB
    bf16*  WcT  = (bf16*)(w + 83886080);      // (512,2048) 2 MiB (Wout@W1 fold)
    bf16*  W1T  = (bf16*)(w + 85983232);      // (512,1024) 1 MiB
    bf16*  W2T  = (bf16*)(w + 87031808);      // (256,512) 256 KiB
    bf16*  WxT  = (bf16*)(w + 87293952);      // (96,2048) 384 KiB
    bf16*  WdT  = (bf16*)(w + 87687168);      // (2048,64) 256 KiB
    float* proj = (float*)(w + 87949312);     // (M_,96) fp32 1.5 MiB
    bf16*  Wob  = (bf16*)(w + 89522176);      // (2048,1024) 4 MiB; end 93716480

    dim3 blk(256);

    // 1. all input preprocessing in one dispatch (also zeroes proj)
    prep_kernel<<<dim3(11200), blk, 0, stream>>>(
        spatial, temporal, xb, proj, W_in, WinT, W_out, Wob,
        W_x, WxT, W_dt, WdT, W1, W1T, W2, W2T);

    // 2. G1 (+fused conv/silu +fused G2 partials) + Wc fold, one dispatch
    gemm_g1_conv<<<dim3(36, 32), blk, 0, stream>>>(
        xb, WinT, xcb, zb, conv_w, conv_b, W1T, Wob, WcT, WxT, proj);

    // 3. Fused G3 + selective scan + skip + gating, y in-place over xcb
    scan_g3_kernel<<<dim3(8, 64), blk, 0, stream>>>(
        proj, WdT, b_dt, xcb, zb, A_log, D_skip);

    // 4. G4': h1 = relu(y @ Wc + b1)  (4096 x 512, K=2048), full-K,
    //    BN=64 -> 256 blocks, bf16 out — no partial round-trip.
    gemm_mfma<128, 64, 1, 1><<<dim3(8, 32), blk, 0, stream>>>(
        xcb, 2048, WcT, 2048, h1, 512, b1, 512, 2048);

    // 5. G6: h2 = relu(h1 @ W2 + b2)  (4096 x 256, K=512), full-K,
    //    BN=64 -> 128 blocks, bf16 out.
    gemm_mfma<128, 64, 1, 1><<<dim3(4, 32), blk, 0, stream>>>(
        h1, 512, W2T, 512, h2, 256, b2, 256, 512);

    // 6. head: out = h2 @ W3 + b3
    head_kernel<<<dim3(1024), blk, 0, stream>>>(h2, W3, b3, out);
}

// Round 16
// 268.655 us; speedup vs baseline: 1.0512x; 1.0512x over previous
//
#include <hip/hip_runtime.h>
#include <hip/hip_bf16.h>
#include <math.h>

// Problem constants
#define B_   64
#define T_   64
#define E_   512
#define DM   1024   // d_model
#define DI   2048   // d_inner
#define DS   16     // d_state
#define DTR  64     // dt_rank
#define M_   4096   // B*T rows

typedef __hip_bfloat16 bf16;
typedef __attribute__((ext_vector_type(8))) short bf16x8;   // 8 bf16 = 4 VGPRs
typedef __attribute__((ext_vector_type(4))) float f32x4;

// ---------------------------------------------------------------------------
// bf16 MFMA GEMM (split-K, fp32 partials): used by G4'.
// Best-measured core (R3..R14): BK=32, 256 threads, 2x2 wave grid, both
// operands staged via global_load_lds width=16 into linear [row][32] LDS.
// R15's full-K BN=64 variant regressed (block-parallelism beats traffic
// savings on this core) — split-K x4 with 512 blocks is the measured best.
// ---------------------------------------------------------------------------
template<int SPLITK, int BM, int BN>
__global__ __launch_bounds__(256) void gemm_mfma(
    const bf16* __restrict__ A, int lda,
    const bf16* __restrict__ Bt, int ldb,
    float* __restrict__ Cv, int ldc,
    int Ndim, int Kdim)
{
    __shared__ __align__(16) bf16 As[BM * 32];
    __shared__ __align__(16) bf16 Bs[BN * 32];
    const int tid  = threadIdx.x;
    const int wave = tid >> 6;
    const int lane = tid & 63;
    const int bm = blockIdx.y * BM;
    const int bn = blockIdx.x * BN;
    const int lrow = lane >> 2;               // 0..15
    const int lkc  = (lane & 3) * 8;          // k element offset 0,8,16,24
    constexpr int RPW = (BM + BN) / 4;        // rows staged per wave
    constexpr int NI  = RPW / 16;             // issues per wave
    constexpr int WMT = BM / 32;
    constexpr int WNT = BN / 32;
    const int wm = (wave >> 1) * (BM / 2);
    const int wn = (wave & 1) * (BN / 2);
    const int fm = lane & 15;
    const int fq = lane >> 4;

    int kstart = 0, kend = Kdim;
    if (SPLITK > 1) {
        int chunk = Kdim / SPLITK;
        kstart = blockIdx.z * chunk;
        kend = kstart + chunk;
    }

    f32x4 acc[WMT][WNT];
    #pragma unroll
    for (int i = 0; i < WMT; ++i)
        #pragma unroll
        for (int j = 0; j < WNT; ++j)
            acc[i][j] = (f32x4){0.f, 0.f, 0.f, 0.f};

    for (int k0 = kstart; k0 < kend; k0 += 32) {
        #pragma unroll
        for (int i = 0; i < NI; ++i) {
            int rowbase = wave * RPW + i * 16;   // wave-uniform
            int row = rowbase + lrow;
            if (rowbase < BM) {
                const bf16* ga = A + (size_t)(bm + row) * lda + k0 + lkc;
                __builtin_amdgcn_global_load_lds(
                    (const __attribute__((address_space(1))) void*)ga,
                    (__attribute__((address_space(3))) void*)&As[rowbase * 32],
                    16, 0, 0);
            } else {
                int brow = bn + row - BM;
                if (brow >= Ndim) brow = Ndim - 1;
                const bf16* gb = Bt + (size_t)brow * ldb + k0 + lkc;
                __builtin_amdgcn_global_load_lds(
                    (const __attribute__((address_space(1))) void*)gb,
                    (__attribute__((address_space(3))) void*)&Bs[(rowbase - BM) * 32],
                    16, 0, 0);
            }
        }
        __syncthreads();
        bf16x8 a[WMT], b[WNT];
        #pragma unroll
        for (int i = 0; i < WMT; ++i)
            a[i] = *(const bf16x8*)&As[(wm + i * 16 + fm) * 32 + fq * 8];
        #pragma unroll
        for (int j = 0; j < WNT; ++j)
            b[j] = *(const bf16x8*)&Bs[(wn + j * 16 + fm) * 32 + fq * 8];
        #pragma unroll
        for (int i = 0; i < WMT; ++i)
            #pragma unroll
            for (int j = 0; j < WNT; ++j)
                acc[i][j] = __builtin_amdgcn_mfma_f32_16x16x32_bf16(
                    a[i], b[j], acc[i][j], 0, 0, 0);
        __syncthreads();
    }

    size_t zoff = (SPLITK > 1) ? (size_t)blockIdx.z * M_ * ldc : 0;
    #pragma unroll
    for (int i = 0; i < WMT; ++i) {
        int rowb = bm + wm + i * 16 + fq * 4;
        #pragma unroll
        for (int j = 0; j < WNT; ++j) {
            int col = bn + wn + j * 16 + fm;
            if (col < Ndim) {
                #pragma unroll
                for (int r = 0; r < 4; ++r)
                    Cv[zoff + (size_t)(rowb + r) * ldc + col] = acc[i][j][r];
            }
        }
    }
}

// ---------------------------------------------------------------------------
// G1 specialized + Wc fold merged + G2 fused (R14). Grid (36, 32):
//   blockIdx.x <  32: xz = xb @ W_in tile; conv+silu fused epilogue (R8);
//     then (xi blocks) the G2 partial  proj[bm.., 0:96) += tile @ WxTᵀ
//     via per-wave MFMA on the LDS-resident conv output, atomicAdd to proj.
//   blockIdx.x >= 32: WcT = W1T @ W_outᵀ (the W_out@W1 weight fold).
//     R16: B-operand staged directly from fp32 W_out (VALU cvt -> ds_write),
//     eliminating the Wob convert buffer + its prep blocks. Same rounding.
// ---------------------------------------------------------------------------
__global__ __launch_bounds__(256) void gemm_g1_conv(
    const bf16* __restrict__ A,      // xb (M_,1024)
    const bf16* __restrict__ Bt,     // WinT (4096,1024)
    bf16* __restrict__ xcb,          // (M_,2048) silu(conv(xi))
    bf16* __restrict__ zb,           // (M_,2048) z
    const float* __restrict__ conv_w,
    const float* __restrict__ conv_b,
    const bf16* __restrict__ W1T,    // (512,1024)
    const float* __restrict__ W_out, // (2048,1024) fp32
    bf16* __restrict__ WcT,          // (512,2048) out
    const bf16* __restrict__ WxT,    // (96,2048)
    float* __restrict__ proj)        // (M_,96) fp32, pre-zeroed; += G2 partials
{
    constexpr int XS = 136;                       // padded X stride (elems)
    __shared__ __align__(16) bf16 smem[128 * XS]; // 34816 B
    const int tid  = threadIdx.x;
    const int wave = tid >> 6;
    const int lane = tid & 63;
    const int lrow = lane >> 2;
    const int lkc  = (lane & 3) * 8;
    const int wm = (wave >> 1) * 64;
    const int fm = lane & 15;
    const int fq = lane >> 4;

    if (blockIdx.x >= 32) {
        // ---------------- fold path: BM=128, BN=64 ----------------
        const int fbm = (blockIdx.x - 32) * 128;   // over M=512
        const int fbn = blockIdx.y * 64;           // over N=2048
        const int fwn = (wave & 1) * 32;
        const int arow = tid >> 2;                 // 0..63 (B fp32 staging)
        const int ak   = (tid & 3) * 8;            // 0,8,16,24
        f32x4 facc[4][2];
        #pragma unroll
        for (int i = 0; i < 4; ++i)
            #pragma unroll
            for (int j = 0; j < 2; ++j)
                facc[i][j] = (f32x4){0.f, 0.f, 0.f, 0.f};

        for (int k0 = 0; k0 < 1024; k0 += 32) {
            // A: W1T bf16, 128 rows, 2 async issues per wave
            #pragma unroll
            for (int i = 0; i < 2; ++i) {
                int rowbase = wave * 32 + i * 16;  // wave-uniform
                const bf16* ga = W1T + (size_t)(fbm + rowbase + lrow) * 1024
                                     + k0 + lkc;
                __builtin_amdgcn_global_load_lds(
                    (const __attribute__((address_space(1))) void*)ga,
                    (__attribute__((address_space(3))) void*)&smem[rowbase * 32],
                    16, 0, 0);
            }
            // B: W_out fp32 (64 rows x 32 k) -> bf16 cvt -> Bs
            {
                const float* gb = W_out + (size_t)(fbn + arow) * 1024 + k0 + ak;
                float4 v0 = *(const float4*)gb;
                float4 v1 = *(const float4*)(gb + 4);
                bf16 o[8] = {
                    __float2bfloat16(v0.x), __float2bfloat16(v0.y),
                    __float2bfloat16(v0.z), __float2bfloat16(v0.w),
                    __float2bfloat16(v1.x), __float2bfloat16(v1.y),
                    __float2bfloat16(v1.z), __float2bfloat16(v1.w)};
                *(bf16x8*)&smem[4096 + arow * 32 + ak] = *(const bf16x8*)o;
            }
            __syncthreads();
            bf16x8 a[4], b[2];
            #pragma unroll
            for (int i = 0; i < 4; ++i)
                a[i] = *(const bf16x8*)&smem[(wm + i * 16 + fm) * 32 + fq * 8];
            #pragma unroll
            for (int j = 0; j < 2; ++j)
                b[j] = *(const bf16x8*)&smem[4096 + (fwn + j * 16 + fm) * 32 + fq * 8];
            #pragma unroll
            for (int i = 0; i < 4; ++i)
                #pragma unroll
                for (int j = 0; j < 2; ++j)
                    facc[i][j] = __builtin_amdgcn_mfma_f32_16x16x32_bf16(
                        a[i], b[j], facc[i][j], 0, 0, 0);
            __syncthreads();
        }
        #pragma unroll
        for (int i = 0; i < 4; ++i) {
            int rowb = fbm + wm + i * 16 + fq * 4;
            #pragma unroll
            for (int j = 0; j < 2; ++j) {
                int col = fbn + fwn + j * 16 + fm;
                #pragma unroll
                for (int r = 0; r < 4; ++r)
                    WcT[(size_t)(rowb + r) * 2048 + col] =
                        __float2bfloat16(facc[i][j][r]);
            }
        }
        return;
    }

    // ---------------- G1 path (unchanged R8 core) ----------------
    const int bm = blockIdx.y * 128;
    const int bn = blockIdx.x * 128;
    const int wn = (wave & 1) * 64;

    f32x4 acc[4][4];
    #pragma unroll
    for (int i = 0; i < 4; ++i)
        #pragma unroll
        for (int j = 0; j < 4; ++j)
            acc[i][j] = (f32x4){0.f, 0.f, 0.f, 0.f};

    for (int k0 = 0; k0 < 1024; k0 += 32) {
        #pragma unroll
        for (int i = 0; i < 4; ++i) {
            int rowbase = wave * 64 + i * 16;     // wave-uniform
            int row = rowbase + lrow;
            if (rowbase < 128) {
                const bf16* ga = A + (size_t)(bm + row) * 1024 + k0 + lkc;
                __builtin_amdgcn_global_load_lds(
                    (const __attribute__((address_space(1))) void*)ga,
                    (__attribute__((address_space(3))) void*)&smem[rowbase * 32],
                    16, 0, 0);
            } else {
                const bf16* gb = Bt + (size_t)(bn + row - 128) * 1024 + k0 + lkc;
                __builtin_amdgcn_global_load_lds(
                    (const __attribute__((address_space(1))) void*)gb,
                    (__attribute__((address_space(3))) void*)&smem[4096 + (rowbase - 128) * 32],
                    16, 0, 0);
            }
        }
        __syncthreads();
        bf16x8 a[4], b[4];
        #pragma unroll
        for (int i = 0; i < 4; ++i)
            a[i] = *(const bf16x8*)&smem[(wm + i * 16 + fm) * 32 + fq * 8];
        #pragma unroll
        for (int j = 0; j < 4; ++j)
            b[j] = *(const bf16x8*)&smem[4096 + (wn + j * 16 + fm) * 32 + fq * 8];
        #pragma unroll
        for (int i = 0; i < 4; ++i)
            #pragma unroll
            for (int j = 0; j < 4; ++j)
                acc[i][j] = __builtin_amdgcn_mfma_f32_16x16x32_bf16(
                    a[i], b[j], acc[i][j], 0, 0, 0);
        __syncthreads();   // As/Bs region dead -> reusable as conv buffer
    }

    if (bn < 2048) {
        #pragma unroll
        for (int i = 0; i < 4; ++i) {
            int rowb = wm + i * 16 + fq * 4;
            #pragma unroll
            for (int j = 0; j < 4; ++j) {
                int col = wn + j * 16 + fm;
                #pragma unroll
                for (int r = 0; r < 4; ++r)
                    smem[(rowb + r) * XS + col] = __float2bfloat16(acc[i][j][r]);
            }
        }
        __syncthreads();
        {
            int col = tid & 127;
            int seq = tid >> 7;                   // 0 or 1
            int gcol = bn + col;
            float4 cw = *(const float4*)&conv_w[gcol * 4];
            float cb = conv_b[gcol];
            float w0 = 0.f, w1 = 0.f, w2 = 0.f;
            int base = seq * 64;
            for (int t = 0; t < 64; ++t) {
                int idx = (base + t) * XS + col;
                float cur = __bfloat162float(smem[idx]);
                float cacc = cb;
                cacc = fmaf(w0, cw.x, cacc); cacc = fmaf(w1, cw.y, cacc);
                cacc = fmaf(w2, cw.z, cacc); cacc = fmaf(cur, cw.w, cacc);
                smem[idx] = __float2bfloat16(__fdividef(cacc, 1.f + __expf(-cacc)));
                w0 = w1; w1 = w2; w2 = cur;
            }
        }
        __syncthreads();
        // coalesced bf16x8 store -> xcb
        #pragma unroll
        for (int it = 0; it < 8; ++it) {
            int g = it * 256 + tid;               // 2048 groups of 8
            int row = g >> 4;
            int cg = (g & 15) * 8;
            bf16x8 v = *(const bf16x8*)&smem[row * XS + cg];
            *(bf16x8*)&xcb[(size_t)(bm + row) * 2048 + bn + cg] = v;
        }
        // ---- fused G2 partial: proj[bm+m, n] += sum_k tile[m,k]*WxT[n,bn+k]
        {
            const int mw = wave * 32;
            f32x4 dacc[2][6];
            #pragma unroll
            for (int i = 0; i < 2; ++i)
                #pragma unroll
                for (int j = 0; j < 6; ++j)
                    dacc[i][j] = (f32x4){0.f, 0.f, 0.f, 0.f};
            #pragma unroll
            for (int kit = 0; kit < 4; ++kit) {
                bf16x8 bfrag[6], afrag[2];
                #pragma unroll
                for (int j = 0; j < 6; ++j)
                    bfrag[j] = *(const bf16x8*)(WxT
                        + (size_t)(j * 16 + fm) * 2048 + bn + kit * 32 + fq * 8);
                #pragma unroll
                for (int i = 0; i < 2; ++i)
                    afrag[i] = *(const bf16x8*)&smem[
                        (mw + i * 16 + fm) * XS + kit * 32 + fq * 8];
                #pragma unroll
                for (int i = 0; i < 2; ++i)
                    #pragma unroll
                    for (int j = 0; j < 6; ++j)
                        dacc[i][j] = __builtin_amdgcn_mfma_f32_16x16x32_bf16(
                            afrag[i], bfrag[j], dacc[i][j], 0, 0, 0);
            }
            #pragma unroll
            for (int i = 0; i < 2; ++i) {
                int rowb = bm + mw + i * 16 + fq * 4;
                #pragma unroll
                for (int j = 0; j < 6; ++j) {
                    int n = j * 16 + fm;
                    #pragma unroll
                    for (int r = 0; r < 4; ++r)
                        atomicAdd(&proj[(size_t)(rowb + r) * 96 + n],
                                  dacc[i][j][r]);
                }
            }
        }
    } else {
        #pragma unroll
        for (int i = 0; i < 4; ++i) {
            int rowb = bm + wm + i * 16 + fq * 4;
            #pragma unroll
            for (int j = 0; j < 4; ++j) {
                int col = bn - 2048 + wn + j * 16 + fm;
                #pragma unroll
                for (int r = 0; r < 4; ++r)
                    zb[(size_t)(rowb + r) * 2048 + col] =
                        __float2bfloat16(acc[i][j][r]);
            }
        }
    }
}

// ---------------------------------------------------------------------------
// Fused G3 + selective scan (R13). Grid (8, 64).
// ---------------------------------------------------------------------------
__global__ __launch_bounds__(256) void scan_g3_kernel(
    const float* __restrict__ proj,   // (M_,96): [0:64) dt_raw, [64:80) B, [80:96) C
    const bf16*  __restrict__ WdT,    // (2048, 64)
    const float* __restrict__ b_dt,   // (2048)
    bf16* __restrict__ xcy,           // (M_, DI) in: xc, out: gated y
    const bf16*  __restrict__ zb,     // (M_, DI) z
    const float* __restrict__ A_log,  // (DI, 16)
    const float* __restrict__ D_skip) // (DI)
{
    __shared__ float BC[64][32];                  // 8 KB
    __shared__ __align__(16) bf16 Adt[64 * 64];   // 8 KB (dt_raw bf16)
    __shared__ __align__(16) bf16 Bdt[256 * 64];  // 32 KB WdT slice; later dt_s
    const int tid  = threadIdx.x;
    const int wave = tid >> 6;
    const int lane = tid & 63;
    const int b  = blockIdx.y;        // 0..63
    const int dg = blockIdx.x;        // d in [dg*256, dg*256+256)
    const int fm = lane & 15;
    const int fq = lane >> 4;

    // BC staging
    for (int i = tid; i < 64 * 32; i += 256) {
        int t = i >> 5, c = i & 31;
        BC[t][c] = proj[(size_t)(b * 64 + t) * 96 + 64 + c];
    }
    // A staging: dt_raw (64 rows x 64 k) fp32 -> bf16
    {
        int arow = tid >> 2;              // 0..63
        int ak = (tid & 3) * 16;          // 0,16,32,48
        const float* ga = proj + (size_t)(b * 64 + arow) * 96 + ak;
        float4 v0 = *(const float4*)(ga + 0);
        float4 v1 = *(const float4*)(ga + 4);
        float4 v2 = *(const float4*)(ga + 8);
        float4 v3 = *(const float4*)(ga + 12);
        bf16 o[16] = {
            __float2bfloat16(v0.x), __float2bfloat16(v0.y),
            __float2bfloat16(v0.z), __float2bfloat16(v0.w),
            __float2bfloat16(v1.x), __float2bfloat16(v1.y),
            __float2bfloat16(v1.z), __float2bfloat16(v1.w),
            __float2bfloat16(v2.x), __float2bfloat16(v2.y),
            __float2bfloat16(v2.z), __float2bfloat16(v2.w),
            __float2bfloat16(v3.x), __float2bfloat16(v3.y),
            __float2bfloat16(v3.z), __float2bfloat16(v3.w)};
        *(bf16x8*)&Adt[arow * 64 + ak]     = *(const bf16x8*)&o[0];
        *(bf16x8*)&Adt[arow * 64 + ak + 8] = *(const bf16x8*)&o[8];
    }
    // B staging: WdT rows [dg*256, +256). Row = 64 bf16 = 128 B -> 8 lanes
    // of 16 B per row -> 8 rows per issue -> 8 issues per wave (64 rows).
    #pragma unroll
    for (int i = 0; i < 8; ++i) {
        int rowbase = wave * 64 + i * 8;      // wave-uniform
        const bf16* gb = WdT + (size_t)(dg * 256 + rowbase + (lane >> 3)) * 64
                             + (lane & 7) * 8;
        __builtin_amdgcn_global_load_lds(
            (const __attribute__((address_space(1))) void*)gb,
            (__attribute__((address_space(3))) void*)&Bdt[rowbase * 64],
            16, 0, 0);
    }
    __syncthreads();

    // MFMA: M=64(t), N=256(d), K=64. Wave w covers d-range [w*64, w*64+64).
    f32x4 acc[4][4];
    #pragma unroll
    for (int i = 0; i < 4; ++i)
        #pragma unroll
        for (int j = 0; j < 4; ++j)
            acc[i][j] = (f32x4){0.f, 0.f, 0.f, 0.f};
    #pragma unroll
    for (int k0 = 0; k0 < 64; k0 += 32) {
        bf16x8 a[4], bfr[4];
        #pragma unroll
        for (int i = 0; i < 4; ++i)
            a[i] = *(const bf16x8*)&Adt[(i * 16 + fm) * 64 + k0 + fq * 8];
        #pragma unroll
        for (int j = 0; j < 4; ++j)
            bfr[j] = *(const bf16x8*)&Bdt[(wave * 64 + j * 16 + fm) * 64 + k0 + fq * 8];
        #pragma unroll
        for (int i = 0; i < 4; ++i)
            #pragma unroll
            for (int j = 0; j < 4; ++j)
                acc[i][j] = __builtin_amdgcn_mfma_f32_16x16x32_bf16(
                    a[i], bfr[j], acc[i][j], 0, 0, 0);
    }
    __syncthreads();                      // all Bdt reads done
    bf16* dt_s = Bdt;                     // alias: dt_s[t*256 + dlocal]
    #pragma unroll
    for (int j = 0; j < 4; ++j) {
        int dloc = wave * 64 + j * 16 + fm;
        float bv = b_dt[dg * 256 + dloc];
        #pragma unroll
        for (int i = 0; i < 4; ++i) {
            #pragma unroll
            for (int r = 0; r < 4; ++r) {
                int t = i * 16 + fq * 4 + r;
                float v = acc[i][j][r] + bv;
                v = (v > 20.f) ? v : __logf(1.f + __expf(v));   // softplus
                dt_s[t * 256 + dloc] = __float2bfloat16(v);
            }
        }
    }
    __syncthreads();

    // ---- scan main loop (R9 semantics; dt from LDS) ----
    const int d = dg * 256 + tid;
    float av[16];
    const float4* alp = (const float4*)(A_log + d * 16);
    *(float4*)&av[0]  = alp[0];
    *(float4*)&av[4]  = alp[1];
    *(float4*)&av[8]  = alp[2];
    *(float4*)&av[12] = alp[3];
    float A[16];
    #pragma unroll
    for (int n = 0; n < 16; ++n) A[n] = -__expf(av[n]);
    const float Dv = D_skip[d];
    float h[16];
    #pragma unroll
    for (int n = 0; n < 16; ++n) h[n] = 0.f;

    #pragma unroll 2
    for (int t = 0; t < T_; ++t) {
        int row = b * T_ + t;
        size_t off = (size_t)row * DI + d;
        float xv = __bfloat162float(xcy[off]);
        float dt = __bfloat162float(dt_s[t * 256 + tid]);
        float dtx = dt * xv;
        float y = 0.f;
        #pragma unroll
        for (int n = 0; n < 16; ++n) {
            float dA = __expf(dt * A[n]);
            h[n] = fmaf(dA, h[n], dtx * BC[t][n]);
            y = fmaf(h[n], BC[t][16 + n], y);
        }
        float sk = fmaf(xv, Dv, y);
        float z = __bfloat162float(zb[off]);
        float g = __fdividef(z, 1.f + __expf(-z));          // silu(z)
        xcy[off] = __float2bfloat16(sk * g);
    }
}

// ---------------------------------------------------------------------------
// G6 with redp5 fused into A-staging: A = relu(sum_4 p5 + b1) cast bf16.
// BM=128, BN=128, split-K x4 over K=512 -> grid (2, 32, 4) = 256 blocks.
// ---------------------------------------------------------------------------
__global__ __launch_bounds__(256) void gemm_g6(
    const float* __restrict__ p5,     // 4 slices, slice stride 2097152 floats
    const bf16* __restrict__ W2T,     // (256, 512)
    float* __restrict__ p6,           // 4 slices out, stride 1048576 floats
    const float* __restrict__ b1)     // (512)
{
    __shared__ __align__(16) bf16 As[128 * 32];
    __shared__ __align__(16) bf16 Bs[128 * 32];
    const int tid  = threadIdx.x;
    const int wave = tid >> 6;
    const int lane = tid & 63;
    const int bm = blockIdx.y * 128;
    const int bn = blockIdx.x * 128;
    const int lrow = lane >> 2;
    const int lkc  = (lane & 3) * 8;
    const int wm = (wave >> 1) * 64;
    const int wn = (wave & 1) * 64;
    const int fm = lane & 15;
    const int fq = lane >> 4;
    const int kstart = blockIdx.z * 128;

    f32x4 acc[4][4];
    #pragma unroll
    for (int i = 0; i < 4; ++i)
        #pragma unroll
        for (int j = 0; j < 4; ++j)
            acc[i][j] = (f32x4){0.f, 0.f, 0.f, 0.f};

    for (int k0 = kstart; k0 < kstart + 128; k0 += 32) {
        // B staging: 128 rows via global_load_lds (2 issues/wave)
        #pragma unroll
        for (int i = 0; i < 2; ++i) {
            int rowbase = wave * 32 + i * 16;     // wave-uniform
            const bf16* gb = W2T + (size_t)(bn + rowbase + lrow) * 512 + k0 + lkc;
            __builtin_amdgcn_global_load_lds(
                (const __attribute__((address_space(1))) void*)gb,
                (__attribute__((address_space(3))) void*)&Bs[rowbase * 32],
                16, 0, 0);
        }
        // A staging: relu(sum_4 p5 + b1) -> bf16.
        #pragma unroll
        for (int p = 0; p < 4; ++p) {
            int idx = p * 256 + tid;              // 0..1023
            int arow = idx >> 3;                  // 0..127
            int ak4 = (idx & 7) * 4;              // 0..28
            const float* ga = p5 + (size_t)(bm + arow) * 512 + k0 + ak4;
            float4 u0 = *(const float4*)ga;
            float4 u1 = *(const float4*)(ga + 2097152);
            float4 u2 = *(const float4*)(ga + 4194304);
            float4 u3 = *(const float4*)(ga + 6291456);
            float4 bb = *(const float4*)(b1 + k0 + ak4);
            bf16 o[4] = {
                __float2bfloat16(fmaxf(u0.x + u1.x + u2.x + u3.x + bb.x, 0.f)),
                __float2bfloat16(fmaxf(u0.y + u1.y + u2.y + u3.y + bb.y, 0.f)),
                __float2bfloat16(fmaxf(u0.z + u1.z + u2.z + u3.z + bb.z, 0.f)),
                __float2bfloat16(fmaxf(u0.w + u1.w + u2.w + u3.w + bb.w, 0.f))};
            *(short4*)&As[arow * 32 + ak4] = *(const short4*)o;
        }
        __syncthreads();
        bf16x8 a[4], b[4];
        #pragma unroll
        for (int i = 0; i < 4; ++i)
            a[i] = *(const bf16x8*)&As[(wm + i * 16 + fm) * 32 + fq * 8];
        #pragma unroll
        for (int j = 0; j < 4; ++j)
            b[j] = *(const bf16x8*)&Bs[(wn + j * 16 + fm) * 32 + fq * 8];
        #pragma unroll
        for (int i = 0; i < 4; ++i)
            #pragma unroll
            for (int j = 0; j < 4; ++j)
                acc[i][j] = __builtin_amdgcn_mfma_f32_16x16x32_bf16(
                    a[i], b[j], acc[i][j], 0, 0, 0);
        __syncthreads();
    }

    size_t zoff = (size_t)blockIdx.z * M_ * 256;
    #pragma unroll
    for (int i = 0; i < 4; ++i) {
        int rowb = bm + wm + i * 16 + fq * 4;
        #pragma unroll
        for (int j = 0; j < 4; ++j) {
            int col = bn + wn + j * 16 + fm;
            #pragma unroll
            for (int r = 0; r < 4; ++r)
                p6[zoff + (size_t)(rowb + r) * 256 + col] = acc[i][j][r];
        }
    }
}

// ---------------------------------------------------------------------------
// prep: concat->bf16 + zero proj (blocks [0,4096)), transposes of
// W_x/W_dt/W1/W2 ([4096,5056)) and W_in ([5056,9152)).
// (R16: W_out convert branch removed — fold stages fp32 W_out directly.)
// ---------------------------------------------------------------------------
__global__ __launch_bounds__(256) void prep_kernel(
    const float* __restrict__ sp, const float* __restrict__ tp,
    bf16* __restrict__ xb, float* __restrict__ proj,
    const float* __restrict__ W_in,  bf16* __restrict__ WinT,
    const float* __restrict__ W_x,   bf16* __restrict__ WxT,
    const float* __restrict__ W_dt,  bf16* __restrict__ WdT,
    const float* __restrict__ W1,    bf16* __restrict__ W1T,
    const float* __restrict__ W2,    bf16* __restrict__ W2T)
{
    __shared__ float tile[32][33];
    const int b = blockIdx.x;
    const int tid = threadIdx.x;
    if (b < 4096) {
        int idx = b * 256 + tid;
        int row = idx >> 8;
        int c4 = (idx & 255) * 4;
        const float* src = (c4 < 512) ? (sp + (size_t)row * 512 + c4)
                                      : (tp + (size_t)row * 512 + (c4 - 512));
        float4 v = *(const float4*)src;
        bf16* dst = xb + (size_t)row * 1024 + c4;
        dst[0] = __float2bfloat16(v.x); dst[1] = __float2bfloat16(v.y);
        dst[2] = __float2bfloat16(v.z); dst[3] = __float2bfloat16(v.w);
        if (idx < 98304)   // zero proj (393216 floats) for fused-G2 atomicAdd
            *(float4*)(proj + (size_t)idx * 4) = make_float4(0.f, 0.f, 0.f, 0.f);
        return;
    }
    const float* W; bf16* Wt; int K, N, tb;
    if      (b < 4288) { W = W_x;  Wt = WxT;  K = 2048; N = 96;   tb = b - 4096; }
    else if (b < 4416) { W = W_dt; Wt = WdT;  K = 64;   N = 2048; tb = b - 4288; }
    else if (b < 4928) { W = W1;   Wt = W1T;  K = 1024; N = 512;  tb = b - 4416; }
    else if (b < 5056) { W = W2;   Wt = W2T;  K = 512;  N = 256;  tb = b - 4928; }
    else               { W = W_in; Wt = WinT; K = 1024; N = 4096; tb = b - 5056; }
    int nb = N / 32;
    int bn = (tb % nb) * 32, bk = (tb / nb) * 32;
    int tx = tid & 31, ty = tid >> 5;
    #pragma unroll
    for (int i = 0; i < 32; i += 8)
        tile[ty + i][tx] = W[(size_t)(bk + ty + i) * N + bn + tx];
    __syncthreads();
    #pragma unroll
    for (int i = 0; i < 32; i += 8)
        Wt[(size_t)(bn + ty + i) * K + bk + tx] = __float2bfloat16(tile[tx][ty + i]);
}

// ---------------------------------------------------------------------------
// Fused tail: h2 = relu(reduce_P(p6) + b2); out = h2 @ W3 + b3.
// ---------------------------------------------------------------------------
template<int P>
__global__ __launch_bounds__(256) void head_kernel(
    const float* __restrict__ p6, int stride,
    const float* __restrict__ b2,
    const float* __restrict__ W3, const float* __restrict__ b3,
    float* __restrict__ out)
{
    int row = blockIdx.x * 4 + (threadIdx.x >> 6);
    int lane = threadIdx.x & 63;
    float acc[6] = {0.f, 0.f, 0.f, 0.f, 0.f, 0.f};
    #pragma unroll
    for (int kk = 0; kk < 4; ++kk) {
        int c = lane + kk * 64;
        size_t off = (size_t)row * 256 + c;
        float s = p6[off];
        #pragma unroll
        for (int p = 1; p < P; ++p) s += p6[(size_t)p * stride + off];
        s = fmaxf(s + b2[c], 0.f);
        #pragma unroll
        for (int n = 0; n < 6; ++n) acc[n] = fmaf(s, W3[c * 6 + n], acc[n]);
    }
    #pragma unroll
    for (int n = 0; n < 6; ++n) {
        float v = acc[n];
        #pragma unroll
        for (int off = 32; off > 0; off >>= 1) v += __shfl_down(v, off);
        if (lane == 0) out[(size_t)row * 6 + n] = v + b3[n];
    }
}

// ---------------------------------------------------------------------------
extern "C" void kernel_launch(void* const* d_in, const int* in_sizes, int n_in,
                              void* d_out, int out_size, void* d_ws, size_t ws_size,
                              hipStream_t stream)
{
    const float* spatial  = (const float*)d_in[0];
    const float* temporal = (const float*)d_in[1];
    const float* W_in     = (const float*)d_in[2];
    const float* conv_w   = (const float*)d_in[3];
    const float* conv_b   = (const float*)d_in[4];
    const float* W_x      = (const float*)d_in[5];
    const float* W_dt     = (const float*)d_in[6];
    const float* b_dt     = (const float*)d_in[7];
    const float* A_log    = (const float*)d_in[8];
    const float* D_skip   = (const float*)d_in[9];
    const float* W_out    = (const float*)d_in[10];
    const float* W1       = (const float*)d_in[11];
    const float* b1       = (const float*)d_in[12];
    const float* W2       = (const float*)d_in[13];
    const float* b2       = (const float*)d_in[14];
    const float* W3       = (const float*)d_in[15];
    const float* b3       = (const float*)d_in[16];
    float* out = (float*)d_out;

    // Workspace layout (bytes), total 89,522,176.
    // p5 (4 slices, 32 MiB) at +33554432..+67108864.
    // p6 (4 slices, 16 MiB) at +67108864 over xb+WinT (dead after G1).
    char* w = (char*)d_ws;
    bf16*  xcb  = (bf16*)(w);                 // (M_,2048) xc -> y (in-place)
    bf16*  zb   = (bf16*)(w + 16777216);      // (M_,2048) 16 MiB
    float* p5   = (float*)(w + 33554432);     // 4x(M_,512) fp32 32 MiB
    bf16*  xb   = (bf16*)(w + 67108864);      // (M_,1024) 8 MiB; dead after G1
    bf16*  WinT = (bf16*)(w + 75497472);      // (4096,1024) 8 MiB; dead after G1
    float* p6   = (float*)(w + 67108864);     // 4x(M_,256) fp32 16 MiB (after G1)
    bf16*  WcT  = (bf16*)(w + 83886080);      // (512,2048) 2 MiB (Wout@W1 fold)
    bf16*  W1T  = (bf16*)(w + 85983232);      // (512,1024) 1 MiB
    bf16*  W2T  = (bf16*)(w + 87031808);      // (256,512) 256 KiB
    bf16*  WxT  = (bf16*)(w + 87293952);      // (96,2048) 384 KiB
    bf16*  WdT  = (bf16*)(w + 87687168);      // (2048,64) 256 KiB
    float* proj = (float*)(w + 87949312);     // (M_,96) fp32 1.5 MiB; end 89522176

    dim3 blk(256);

    // 1. all input preprocessing in one dispatch (also zeroes proj)
    prep_kernel<<<dim3(9152), blk, 0, stream>>>(
        spatial, temporal, xb, proj, W_in, WinT,
        W_x, WxT, W_dt, WdT, W1, W1T, W2, W2T);

    // 2. G1 (+fused conv/silu +fused G2 partials) + Wc fold, one dispatch
    gemm_g1_conv<<<dim3(36, 32), blk, 0, stream>>>(
        xb, WinT, xcb, zb, conv_w, conv_b, W1T, W_out, WcT, WxT, proj);

    // 3. Fused G3 + selective scan + skip + gating, y in-place over xcb
    scan_g3_kernel<<<dim3(8, 64), blk, 0, stream>>>(
        proj, WdT, b_dt, xcb, zb, A_log, D_skip);

    // 4. G4': p5 = y @ Wc   (4096 x 512, K=2048), split-K x4 -> 512 blocks
    gemm_mfma<4, 128, 128><<<dim3(4, 32, 4), blk, 0, stream>>>(
        xcb, 2048, WcT, 2048, p5, 512, 512, 2048);

    // 5. G6 (+fused redp5): p6 = relu(sum_4(p5)+b1) @ W2, split-K x4
    gemm_g6<<<dim3(2, 32, 4), blk, 0, stream>>>(p5, W2T, p6, b1);

    // 6. fused: out = relu(reduce(p6) + b2) @ W3 + b3
    head_kernel<4><<<dim3(1024), blk, 0, stream>>>(
        p6, 1048576, b2, W3, b3, out);
}